// Round 9
// baseline (498.186 us; speedup 1.0000x reference)
//
#include <hip/hip_runtime.h>
#include <hip/hip_cooperative_groups.h>
#include <math.h>

namespace cg = cooperative_groups;

// Problem constants (from reference)
#define BB 8
#define SS 64
#define VV 50257
#define PP 200
#define NW 1571                          // ceil(VV/32) mask words per sequence
#define NT 256                           // threads per block
#define NROW 512                         // B*S rows
#define NCH 3                            // chunks per row
#define Q 4188                           // float4 per chunk (3*4188 = 12564 = max nb)
#define ITQ 17                           // ceil(Q/NT)
#define GRID (NROW * NCH)                // 1536 = exactly 6 blocks/CU on 256 CUs

constexpr float RP   = 1.2f;
constexpr float RPI  = 1.0f / 1.2f;
constexpr float TINV = 1.0f / 0.6f;      // 1/temperature
constexpr float RPT  = RP * TINV;        // exp(x*f) fused factors
constexpr float RPIT = RPI * TINV;

typedef float f32x4 __attribute__((ext_vector_type(4)));

// ---------------------------------------------------------------------------
// COOPERATIVE SINGLE-DISPATCH, TWO STREAMING PHASES.
//
// Ledger r0-r8: EVERY structure (8-32 waves/CU, fused or split) reads at
// 2.6-3.0 TB/s while write-only fills hit 6.7 TB/s -> the read+compute
// stream has a ~3 TB/s plateau independent of occupancy/phasing. What we
// CAN still remove: dispatch drains, read/write phase serialization
// overheads, and redundant traffic. This fuses r6's two kernels via
// grid.sync():
//  phase A: 1536 blocks (512 rows x 3 chunks, 256 thr, 6/CU co-resident).
//           Blocks 0..63 additionally dedupe s=blk: LDS bitmask dedupe,
//           per-b delta sums, publish {mask,allneg} + deltas to ws.
//           All blocks: chunk exp-sum -> wsum[row*8+cc].
//  grid.sync (cooperative; no dispatch drain, blocks stay resident so
//           phase B re-reads hit the same XCD's caches / L3).
//  phase B: li = 1/(3 partials + delta); stage this chunk's bitwords into
//           LDS; stream chunk (L3-hot re-read), factor from bits
//           (penalty is idempotent -> no scatter pass), nt-store.
// Fallbacks: coop launch error -> same phases as two plain dispatches;
//            ws too small -> r8 single-kernel.
// ws layout: [0,16KB) float wsum[512][8] (slots 0-2 partials, 4 delta);
//            [16KB,..) uint2 {mask,allneg}[64][NW]  (~804KB).
// ---------------------------------------------------------------------------

__device__ __forceinline__ void phaseA(
        int blk, int tid,
        const float* __restrict__ logits, const int* __restrict__ prev,
        float* __restrict__ wsum, uint2* __restrict__ bits,
        unsigned* lmask, unsigned* lall, float* dsum, float* red) {
    const int row = blk & (NROW - 1);
    const int cc  = blk >> 9;            // chunk 0..2
    const int s   = row & (SS - 1);
    const bool ded = (blk < SS);         // rows 0..63, chunk 0 -> dedupe s=row

    // dedupe block: zero masks + issue token/scatter loads early
    int   vtok = -1;
    float lv[BB];
    if (ded) {
        for (int i = tid; i < NW; i += NT) { lmask[i] = 0u; lall[i] = 0u; }
        if (tid < BB) dsum[tid] = 0.f;
        if (tid < PP) {
            vtok = prev[s * PP + tid];
            #pragma unroll
            for (int j = 0; j < BB; ++j)
                lv[j] = logits[((size_t)(j * SS + s)) * VV + vtok];
        }
    }

    // streaming chunk sum
    const float* rowp = logits + (size_t)row * VV;
    const int a0   = (4 - (row & 3)) & 3;
    const int nb   = (VV - a0) >> 2;
    const int iend = ((cc + 1) * Q < nb) ? (cc + 1) * Q : nb;
    const f32x4* body = (const f32x4*)(rowp + a0);

    float ax = 0.f, ay = 0.f, az = 0.f, aw = 0.f;
    #pragma unroll
    for (int k = 0; k < ITQ; ++k) {
        int i = cc * Q + k * NT + tid;
        if (i < iend) {
            f32x4 x = body[i];
            ax += __expf(x.x * TINV);
            ay += __expf(x.y * TINV);
            az += __expf(x.z * TINV);
            aw += __expf(x.w * TINV);
        }
    }
    float acc = (ax + ay) + (az + aw);
    if (cc == 0) {
        const int tail   = VV - a0 - (nb << 2);
        const int tstart = a0 + (nb << 2);
        if (tid < a0)                   acc += __expf(rowp[tid] * TINV);
        if (tid >= 4 && tid < 4 + tail) acc += __expf(rowp[tstart + tid - 4] * TINV);
    }
    #pragma unroll
    for (int off = 1; off < 64; off <<= 1) acc += __shfl_xor(acc, off);
    if ((tid & 63) == 0) red[tid >> 6] = acc;
    __syncthreads();                     // also orders dedupe LDS zeroing
    if (tid == 0) wsum[row * 8 + cc] = (red[0] + red[1]) + (red[2] + red[3]);

    // dedupe resolve + publish (block-uniform branch)
    if (ded) {
        bool winner = false;
        bool alln   = false;
        if (tid < PP) {
            unsigned bit = 1u << (vtok & 31);
            unsigned old = atomicOr(&lmask[vtok >> 5], bit);
            winner = !(old & bit);
            if (winner) {
                alln = true;
                #pragma unroll
                for (int j = 0; j < BB; ++j) alln = alln && (lv[j] < 0.f);
                if (alln) atomicOr(&lall[vtok >> 5], bit);
            }
        }
        const float ft = alln ? RPT : RPIT;
        #pragma unroll
        for (int j = 0; j < BB; ++j) {
            float d = winner ? (__expf(lv[j] * ft) - __expf(lv[j] * TINV)) : 0.f;
            #pragma unroll
            for (int off = 1; off < 64; off <<= 1) d += __shfl_xor(d, off);
            if ((tid & 63) == 0) atomicAdd(&dsum[j], d);
        }
        __syncthreads();
        uint2* brow = bits + (size_t)s * NW;
        for (int i = tid; i < NW; i += NT)
            brow[i] = make_uint2(lmask[i], lall[i]);
        if (tid < BB) wsum[((tid << 6) + s) * 8 + 4] = dsum[tid];
    }
}

__device__ __forceinline__ void phaseB(
        int blk, int tid,
        const float* __restrict__ logits, const float* __restrict__ wsum,
        const uint2* __restrict__ bits, float* __restrict__ out,
        unsigned* lmask, unsigned* lall) {
    const int row = blk & (NROW - 1);
    const int cc  = blk >> 9;
    const int s   = row & (SS - 1);
    const float* rowp = logits + (size_t)row * VV;
    float*       orow = out    + (size_t)row * VV;
    const int a0   = (4 - (row & 3)) & 3;
    const int nb   = (VV - a0) >> 2;
    const int iend = ((cc + 1) * Q < nb) ? (cc + 1) * Q : nb;
    const f32x4* body  = (const f32x4*)(rowp + a0);
    f32x4*       obody = (f32x4*)(orow + a0);
    const uint2* brow  = bits + (size_t)s * NW;

    const float* wr = wsum + row * 8;
    const float li = 1.0f / (((wr[0] + wr[1]) + (wr[2] + wr[3])) + wr[4]);

    // stage this chunk's bit-words into LDS (~524 words, 4.2KB)
    const int wlo = (a0 + cc * Q * 4) >> 5;
    const int whi = (a0 + (iend << 2) - 1) >> 5;
    const int nwd = whi - wlo + 1;
    for (int i = tid; i < nwd; i += NT) {
        uint2 c = brow[wlo + i];
        lmask[i] = c.x;
        lall[i]  = c.y;
    }
    __syncthreads();

    #pragma unroll
    for (int k = 0; k < ITQ; ++k) {
        int i = cc * Q + k * NT + tid;
        if (i < iend) {
            f32x4 x = body[i];                    // L3/L2-hot re-read
            const int vb = a0 + (i << 2);
            const int w0 = vb >> 5;
            const int w3 = (vb + 3) >> 5;
            const unsigned m0 = lmask[w0 - wlo], A0v = lall[w0 - wlo];
            const unsigned m3 = lmask[w3 - wlo], A3v = lall[w3 - wlo];
            f32x4 o;
            #pragma unroll
            for (int j = 0; j < 4; ++j) {
                const int v = vb + j;
                const unsigned mm = ((v >> 5) == w0) ? m0 : m3;
                const unsigned aa = ((v >> 5) == w0) ? A0v : A3v;
                const unsigned sh = (unsigned)v & 31u;
                const float f = ((mm >> sh) & 1u)
                              ? (((aa >> sh) & 1u) ? RPT : RPIT) : TINV;
                o[j] = __expf(x[j] * f) * li;
            }
            __builtin_nontemporal_store(o, &obody[i]);
        }
    }
    if (cc == 0) {
        const int tail   = VV - a0 - (nb << 2);
        const int tstart = a0 + (nb << 2);
        if (tid < a0) {                          // head: word 0 is staged
            const int v = tid;
            const unsigned sh = (unsigned)v & 31u;
            const float f = ((lmask[0] >> sh) & 1u)
                          ? (((lall[0] >> sh) & 1u) ? RPT : RPIT) : TINV;
            __builtin_nontemporal_store(__expf(rowp[v] * f) * li, &orow[v]);
        }
        if (tid >= 4 && tid < 4 + tail) {        // tail: direct bits read
            const int v = tstart + tid - 4;
            uint2 c = brow[v >> 5];
            const unsigned sh = (unsigned)v & 31u;
            const float f = ((c.x >> sh) & 1u)
                          ? (((c.y >> sh) & 1u) ? RPT : RPIT) : TINV;
            __builtin_nontemporal_store(__expf(rowp[v] * f) * li, &orow[v]);
        }
    }
}

__global__ __launch_bounds__(NT, 6) void k_coop(
        const float* __restrict__ logits, const int* __restrict__ prev,
        float* __restrict__ out, float* __restrict__ wsum,
        uint2* __restrict__ bits) {
    __shared__ unsigned lmask[NW];
    __shared__ unsigned lall[NW];
    __shared__ float    dsum[BB];
    __shared__ float    red[NT / 64];
    const int blk = blockIdx.x, tid = threadIdx.x;
    phaseA(blk, tid, logits, prev, wsum, bits, lmask, lall, dsum, red);
    __threadfence();
    cg::this_grid().sync();
    phaseB(blk, tid, logits, wsum, bits, out, lmask, lall);
}

__global__ __launch_bounds__(NT, 6) void k_a(
        const float* __restrict__ logits, const int* __restrict__ prev,
        float* __restrict__ wsum, uint2* __restrict__ bits) {
    __shared__ unsigned lmask[NW];
    __shared__ unsigned lall[NW];
    __shared__ float    dsum[BB];
    __shared__ float    red[NT / 64];
    phaseA(blockIdx.x, threadIdx.x, logits, prev, wsum, bits,
           lmask, lall, dsum, red);
}

__global__ __launch_bounds__(NT, 6) void k_b(
        const float* __restrict__ logits, const float* __restrict__ wsum,
        const uint2* __restrict__ bits, float* __restrict__ out) {
    __shared__ unsigned lmask[NW];
    __shared__ unsigned lall[NW];
    phaseB(blockIdx.x, threadIdx.x, logits, wsum, bits, out, lmask, lall);
}

// ---------------------------------------------------------------------------
// r8 single-kernel fallback (no workspace needed)
// ---------------------------------------------------------------------------
#define IT 50
__global__ __launch_bounds__(NT) void k_row(
        const float* __restrict__ logits,
        const int*   __restrict__ prev,
        float*       __restrict__ out) {
    __shared__ unsigned lmask[NW];
    __shared__ unsigned lall[NW];
    __shared__ float    red[NT / 64];
    __shared__ float    bcli;

    const int bs  = blockIdx.x;
    const int s   = bs & (SS - 1);
    const int b   = bs >> 6;
    const int tid = threadIdx.x;
    const float* row  = logits + (size_t)bs * VV;
    float*       orow = out    + (size_t)bs * VV;

    const int a0     = (4 - (bs & 3)) & 3;
    const int nb     = (VV - a0) >> 2;
    const int tail   = VV - a0 - (nb << 2);
    const int tstart = a0 + (nb << 2);
    const f32x4* body = (const f32x4*)(row + a0);
    const bool hh = (tid < a0);
    const bool ht = (tid >= 4 && tid < 4 + tail);

    for (int i = tid; i < NW; i += NT) { lmask[i] = 0u; lall[i] = 0u; }
    __syncthreads();

    int   vtok = -1;
    float lv[BB];
    if (tid < PP) {
        vtok = prev[s * PP + tid];
        #pragma unroll
        for (int j = 0; j < BB; ++j)
            lv[j] = logits[((size_t)(j * SS + s)) * VV + vtok];
    }

    float acc = 0.f;
    #pragma unroll
    for (int k = 0; k < IT; ++k) {
        int i = tid + k * NT;
        if (i < nb) {
            f32x4 x = body[i];
            acc += __expf(x.x * TINV) + __expf(x.y * TINV)
                 + __expf(x.z * TINV) + __expf(x.w * TINV);
        }
    }
    if (hh) acc += __expf(row[tid] * TINV);
    if (ht) acc += __expf(row[tstart + tid - 4] * TINV);

    if (tid < PP) {
        unsigned bit = 1u << (vtok & 31);
        unsigned old = atomicOr(&lmask[vtok >> 5], bit);
        if (!(old & bit)) {
            bool alln = true;
            #pragma unroll
            for (int j = 0; j < BB; ++j) alln = alln && (lv[j] < 0.f);
            if (alln) atomicOr(&lall[vtok >> 5], bit);
            const float ft = alln ? RPT : RPIT;
            acc += __expf(lv[b] * ft) - __expf(lv[b] * TINV);
        }
    }

    #pragma unroll
    for (int off = 1; off < 64; off <<= 1) acc += __shfl_xor(acc, off);
    if ((tid & 63) == 0) red[tid >> 6] = acc;
    __syncthreads();
    if (tid == 0) bcli = 1.0f / ((red[0] + red[1]) + (red[2] + red[3]));
    __syncthreads();
    const float li = bcli;

    f32x4* obody = (f32x4*)(orow + a0);
    #pragma unroll
    for (int k = 0; k < IT; ++k) {
        int i = tid + k * NT;
        if (i < nb) {
            f32x4 x = body[i];
            const int vb = a0 + (i << 2);
            const int w0 = vb >> 5, w3 = (vb + 3) >> 5;
            const unsigned m0 = lmask[w0], A0v = lall[w0];
            const unsigned m3 = lmask[w3], A3v = lall[w3];
            f32x4 o;
            #pragma unroll
            for (int j = 0; j < 4; ++j) {
                const int v = vb + j;
                const unsigned mm = ((v >> 5) == w0) ? m0 : m3;
                const unsigned aa = ((v >> 5) == w0) ? A0v : A3v;
                const unsigned sh = (unsigned)v & 31u;
                const float f = ((mm >> sh) & 1u)
                              ? (((aa >> sh) & 1u) ? RPT : RPIT) : TINV;
                o[j] = __expf(x[j] * f) * li;
            }
            __builtin_nontemporal_store(o, &obody[i]);
        }
    }
    if (hh || ht) {
        const int v = hh ? tid : (tstart + tid - 4);
        const unsigned mm = lmask[v >> 5], aa = lall[v >> 5];
        const unsigned sh = (unsigned)v & 31u;
        const float f = ((mm >> sh) & 1u)
                      ? (((aa >> sh) & 1u) ? RPT : RPIT) : TINV;
        __builtin_nontemporal_store(__expf(row[v] * f) * li, &orow[v]);
    }
}

extern "C" void kernel_launch(void* const* d_in, const int* in_sizes, int n_in,
                              void* d_out, int out_size, void* d_ws, size_t ws_size,
                              hipStream_t stream) {
    const float* logits = (const float*)d_in[0];
    const int*   prev   = (const int*)d_in[1];
    float* out = (float*)d_out;

    const size_t need = 16384 + (size_t)SS * NW * sizeof(uint2);  // ~821 KB
    if (d_ws != nullptr && ws_size >= need) {
        float* wsum = (float*)d_ws;
        uint2* bits = (uint2*)((char*)d_ws + 16384);
        void* args[] = { (void*)&logits, (void*)&prev, (void*)&out,
                         (void*)&wsum, (void*)&bits };
        hipError_t e = hipLaunchCooperativeKernel(
            reinterpret_cast<const void*>(&k_coop),
            dim3(GRID), dim3(NT), args, 0, stream);
        if (e != hipSuccess) {
            // cooperative unsupported here (e.g. capture) -> two dispatches
            k_a<<<GRID, NT, 0, stream>>>(logits, prev, wsum, bits);
            k_b<<<GRID, NT, 0, stream>>>(logits, wsum, bits, out);
        }
    } else {
        k_row<<<BB * SS, NT, 0, stream>>>(logits, prev, out);
    }
}